// Round 4
// baseline (56.855 us; speedup 1.0000x reference)
//
#include <hip/hip_runtime.h>
#include <math.h>

#define NP 16384
#define NG 2048
#define NC 17
#define NPPB 64     // points per block (= lanes per wave)
#define NCH 16      // chunk-waves per block
#define CHUNK 128   // NG / NCH
#define FPS 40      // floats per primitive in fp table

#define GRIDSZ 0.4f
#define PCMINX -40.0f
#define PCMINY -40.0f
#define PCMINZ -1.0f
#define SCALE_MULTC 3.0f

// fp layout per primitive (40 floats, 160 B, 16B-aligned):
// [0:3]  murot_i = sum_j mu_j * rot[j*3+i]
// [3:12] rot (row-major)
// [12:15] 1/scales
// [15] opa, [16] 1/u, [17] 1/v, [18] v/u, [19] pad
// [20:37] semantics row, [37:40] pad
__global__ __launch_bounds__(64)
void prep_kernel(const float* __restrict__ means3D, const float* __restrict__ opas,
                 const float* __restrict__ uu, const float* __restrict__ vv,
                 const float* __restrict__ scales, const float* __restrict__ rot3D,
                 const float* __restrict__ semantics,
                 int4* __restrict__ aabb, float* __restrict__ fp) {
    int g = blockIdx.x * 64 + threadIdx.x;
    if (g >= NG) return;
    float mx = means3D[g * 3 + 0], my = means3D[g * 3 + 1], mz = means3D[g * 3 + 2];
    float sx = scales[g * 3 + 0], sy = scales[g * 3 + 1], sz = scales[g * 3 + 2];
    int vx = (int)floorf((mx - PCMINX) / GRIDSZ);
    int vy = (int)floorf((my - PCMINY) / GRIDSZ);
    int vz = (int)floorf((mz - PCMINZ) / GRIDSZ);
    float smax = fmaxf(sx, fmaxf(sy, sz));
    int rad = (int)ceilf(smax * SCALE_MULTC / GRIDSZ);
    if (rad < 1) rad = 1;
    int4 b;
    b.x = max(vx - rad, 0) | ((vx + rad) << 16);
    b.y = max(vy - rad, 0) | ((vy + rad) << 16);
    b.z = max(vz - rad, 0) | ((vz + rad) << 16);
    b.w = 0;
    aabb[g] = b;

    float r[9];
#pragma unroll
    for (int i = 0; i < 9; ++i) r[i] = rot3D[g * 9 + i];
    float* o = fp + (size_t)g * FPS;
    o[0] = mx * r[0] + my * r[3] + mz * r[6];
    o[1] = mx * r[1] + my * r[4] + mz * r[7];
    o[2] = mx * r[2] + my * r[5] + mz * r[8];
#pragma unroll
    for (int i = 0; i < 9; ++i) o[3 + i] = r[i];
    o[12] = 1.0f / sx; o[13] = 1.0f / sy; o[14] = 1.0f / sz;
    o[15] = opas[g];
    o[16] = 1.0f / uu[g];
    o[17] = 1.0f / vv[g];
    o[18] = vv[g] / uu[g];
    o[19] = 0.0f;
#pragma unroll
    for (int c = 0; c < NC; ++c) o[20 + c] = semantics[(size_t)g * NC + c];
    o[37] = 0.0f; o[38] = 0.0f; o[39] = 0.0f;
}

__device__ __forceinline__ void hit_accum(const float* __restrict__ fp, int g,
                                          float px, float py, float pz,
                                          float* acc, float& density, float& logbin) {
    const float4* q = (const float4*)(fp + (size_t)g * FPS);
    float4 q0 = q[0], q1 = q[1], q2 = q[2], q3 = q[3], q4 = q[4];
    float l0 = px * q0.w + py * q1.z + pz * q2.y - q0.x;
    float l1 = px * q1.x + py * q1.w + pz * q2.z - q0.y;
    float l2 = px * q1.y + py * q2.x + pz * q2.w - q0.z;
    float t0 = l0 * q3.x, t1 = l1 * q3.y, t2 = l2 * q3.z;
    float s0 = t0 * t0 + 1e-8f;
    float s1 = t1 * t1 + 1e-8f;
    float s2 = t2 * t2 + 1e-8f;
    float f = __powf(__powf(s0, q4.y) + __powf(s1, q4.y), q4.z) + __powf(s2, q4.x);
    float a = q3.w * __expf(-0.5f * f);
    density += a;
    float sem[NC];
    *(float4*)(sem + 0)  = q[5];
    *(float4*)(sem + 4)  = q[6];
    *(float4*)(sem + 8)  = q[7];
    *(float4*)(sem + 12) = q[8];
    sem[16] = fp[(size_t)g * FPS + 36];
#pragma unroll
    for (int c = 0; c < NC; ++c) acc[c] = fmaf(a, sem[c], acc[c]);
    logbin += __logf(1.0f - fminf(a, 1.0f - 1e-4f));
}

__global__ __launch_bounds__(1024)
void agg_kernel(const float* __restrict__ pts,
                const int4* __restrict__ aabb,
                const float* __restrict__ fp,
                float* __restrict__ out) {
    __shared__ float red[NCH / 2][NPPB][21];
    int tid = threadIdx.x;
    int lane = tid & 63;
    int c = tid >> 6;                                  // chunk id, wave-uniform
    int c_uni = __builtin_amdgcn_readfirstlane(c);     // force SGPR addressing
    int p = blockIdx.x * NPPB + lane;

    float px = pts[p * 3 + 0], py = pts[p * 3 + 1], pz = pts[p * 3 + 2];
    int pix = (int)floorf((px - PCMINX) / GRIDSZ);
    int piy = (int)floorf((py - PCMINY) / GRIDSZ);
    int piz = (int)floorf((pz - PCMINZ) / GRIDSZ);

    const int4* ab = aabb + c_uni * CHUNK;

    // ---- pass 1: branchless AABB hit masks via scalar footprint loads ----
    unsigned m0 = 0u, m1 = 0u, m2 = 0u, m3 = 0u;
#define CHECK32(MW, BASE)                                                     \
    {                                                                         \
        _Pragma("unroll")                                                     \
        for (int i = 0; i < 32; ++i) {                                        \
            int4 b = ab[BASE + i];                                            \
            int in = (pix >= (b.x & 0xffff)) & (pix <= (b.x >> 16)) &         \
                     (piy >= (b.y & 0xffff)) & (piy <= (b.y >> 16)) &         \
                     (piz >= (b.z & 0xffff)) & (piz <= (b.z >> 16));          \
            MW |= (unsigned)in << i;                                          \
        }                                                                     \
    }
    CHECK32(m0, 0)
    CHECK32(m1, 32)
    CHECK32(m2, 64)
    CHECK32(m3, 96)
#undef CHECK32

    // ---- pass 2: process only set bits ----
    float density = 0.0f, logbin = 0.0f;
    float acc[NC];
#pragma unroll
    for (int cc = 0; cc < NC; ++cc) acc[cc] = 0.0f;

    int gbase = c_uni * CHUNK;
#define PROC(MW, BASE)                                                        \
    {                                                                         \
        unsigned m = MW;                                                      \
        while (m) {                                                           \
            int i = __builtin_ctz(m);                                         \
            m &= m - 1;                                                       \
            hit_accum(fp, gbase + BASE + i, px, py, pz, acc, density, logbin);\
        }                                                                     \
    }
    PROC(m0, 0)
    PROC(m1, 32)
    PROC(m2, 64)
    PROC(m3, 96)
#undef PROC

    // ---- in-block tree reduction over the 16 chunks ----
    float part[19];
#pragma unroll
    for (int j = 0; j < NC; ++j) part[j] = acc[j];
    part[17] = density;
    part[18] = logbin;

    if (c >= 8) {
#pragma unroll
        for (int j = 0; j < 19; ++j) red[c - 8][lane][j] = part[j];
    }
    __syncthreads();
    if (c < 8) {
#pragma unroll
        for (int j = 0; j < 19; ++j) red[c][lane][j] += part[j];
    }
    __syncthreads();
    if (c < 4) {
#pragma unroll
        for (int j = 0; j < 19; ++j) red[c][lane][j] += red[c + 4][lane][j];
    }
    __syncthreads();
    if (c < 2) {
#pragma unroll
        for (int j = 0; j < 19; ++j) red[c][lane][j] += red[c + 2][lane][j];
    }
    __syncthreads();
    if (c == 0) {
        float tot[19];
#pragma unroll
        for (int j = 0; j < 19; ++j) tot[j] = red[0][lane][j] + red[1][lane][j];
        float inv = 1.0f / (tot[17] + 1e-9f);
#pragma unroll
        for (int cc = 0; cc < NC; ++cc) out[(size_t)p * NC + cc] = tot[cc] * inv;
        out[(size_t)NP * NC + p] = 1.0f - expf(tot[18]);
        out[(size_t)NP * NC + NP + p] = tot[17];
    }
}

// ---- fallback (ws too small): monolithic kernel ----
__global__ __launch_bounds__(64)
void agg_kernel_fb(const float* __restrict__ pts,
                   const float* __restrict__ means3D,
                   const float* __restrict__ opas,
                   const float* __restrict__ uu,
                   const float* __restrict__ vv,
                   const float* __restrict__ semantics,
                   const float* __restrict__ scales,
                   const float* __restrict__ rot3D,
                   float* __restrict__ out) {
    int p = blockIdx.x * 64 + threadIdx.x;
    if (p >= NP) return;
    float px = pts[p * 3 + 0], py = pts[p * 3 + 1], pz = pts[p * 3 + 2];
    int pix = (int)floorf((px - PCMINX) / GRIDSZ);
    int piy = (int)floorf((py - PCMINY) / GRIDSZ);
    int piz = (int)floorf((pz - PCMINZ) / GRIDSZ);
    float density = 0.0f, logbin = 0.0f;
    float acc[NC];
#pragma unroll
    for (int c = 0; c < NC; ++c) acc[c] = 0.0f;
    for (int g = 0; g < NG; ++g) {
        float cx = means3D[g * 3 + 0], cy = means3D[g * 3 + 1], cz = means3D[g * 3 + 2];
        int mx = (int)floorf((cx - PCMINX) / GRIDSZ);
        int my = (int)floorf((cy - PCMINY) / GRIDSZ);
        int mz = (int)floorf((cz - PCMINZ) / GRIDSZ);
        float smax = fmaxf(scales[g * 3 + 0], fmaxf(scales[g * 3 + 1], scales[g * 3 + 2]));
        int rad = (int)ceilf(smax * SCALE_MULTC / GRIDSZ);
        rad = rad < 1 ? 1 : rad;
        int cheb = max(abs(pix - mx), max(abs(piy - my), abs(piz - mz)));
        if (cheb <= rad) {
            const float* r = rot3D + (size_t)g * 9;
            float dx = px - cx, dy = py - cy, dz = pz - cz;
            float l0 = dx * r[0] + dy * r[3] + dz * r[6];
            float l1 = dx * r[1] + dy * r[4] + dz * r[7];
            float l2 = dx * r[2] + dy * r[5] + dz * r[8];
            float t0 = l0 / scales[g * 3 + 0], t1 = l1 / scales[g * 3 + 1], t2 = l2 / scales[g * 3 + 2];
            float s0 = t0 * t0 + 1e-8f, s1 = t1 * t1 + 1e-8f, s2 = t2 * t2 + 1e-8f;
            float ie1 = 1.0f / uu[g], ie2 = 1.0f / vv[g], e21 = vv[g] / uu[g];
            float f = powf(powf(s0, ie2) + powf(s1, ie2), e21) + powf(s2, ie1);
            float a = opas[g] * expf(-0.5f * f);
            density += a;
            const float* sg = semantics + (size_t)g * NC;
#pragma unroll
            for (int c = 0; c < NC; ++c) acc[c] = fmaf(a, sg[c], acc[c]);
            logbin += log1pf(-fminf(a, 1.0f - 1e-4f));
        }
    }
    float inv = 1.0f / (density + 1e-9f);
#pragma unroll
    for (int c = 0; c < NC; ++c) out[(size_t)p * NC + c] = acc[c] * inv;
    out[(size_t)NP * NC + p] = 1.0f - expf(logbin);
    out[(size_t)NP * NC + NP + p] = density;
}

extern "C" void kernel_launch(void* const* d_in, const int* in_sizes, int n_in,
                              void* d_out, int out_size, void* d_ws, size_t ws_size,
                              hipStream_t stream) {
    const float* pts       = (const float*)d_in[0];
    const float* means3D   = (const float*)d_in[1];
    const float* opas      = (const float*)d_in[2];
    const float* uu        = (const float*)d_in[3];
    const float* vv        = (const float*)d_in[4];
    const float* semantics = (const float*)d_in[5];
    const float* scales    = (const float*)d_in[6];
    const float* rot3D     = (const float*)d_in[7];
    float* out = (float*)d_out;

    size_t need = (size_t)NG * sizeof(int4) + (size_t)NG * FPS * sizeof(float); // ~352 KB
    if (ws_size >= need) {
        int4* aabb = (int4*)d_ws;
        float* fp = (float*)((char*)d_ws + (size_t)NG * sizeof(int4));
        prep_kernel<<<NG / 64, 64, 0, stream>>>(means3D, opas, uu, vv, scales, rot3D,
                                                semantics, aabb, fp);
        agg_kernel<<<NP / NPPB, NCH * 64, 0, stream>>>(pts, aabb, fp, out);
    } else {
        agg_kernel_fb<<<NP / 64, 64, 0, stream>>>(pts, means3D, opas, uu, vv, semantics,
                                                  scales, rot3D, out);
    }
}